// Round 5
// baseline (183.751 us; speedup 1.0000x reference)
//
#include <hip/hip_runtime.h>

// NEAT windowed-DAG forward:
//   values[0:16] = x; for i in 0..511: v = tanh(dot(values[i:i+16], w[i]) + b[i]) * r[i]
//   out = values[T-64:T]  (nodes 448..511)
//
// R5: R4's register prefetch was undone by the scheduler (VGPR stuck at 88),
// and LDS delivery is structurally capped: 10x ds_read_b128/node/CU ~= 100cyc
// on the shared LDS pipe. Params are wave-uniform -> move delivery to the idle
// SCALAR pipe: prep kernel pre-scales params into d_ws; main kernel has NO LDS,
// loads 18 uniform floats/node -> s_load into SGPRs (double-buffered PA/PB),
// v_fma reads the weight directly from the SGPR (1 SGPR/VALU-instr is legal).
// Phase 1 (groups 0..27) is store-free so uniform loads pass noclobber; the 4
// output groups are peeled with compile-time float4 stores.

constexpr int kNodes = 512;
constexpr int kNOut  = 64;
constexpr int kBatch = 32768;
constexpr int kStride = 20;                     // floats per node in ws
constexpr float kScale = 2.8853900817779268f;   // 2*log2(e)

// ---------- prep: pre-scale params into ws [512 x 20 floats = 40960 B] ----------
__global__ __launch_bounds__(256) void neat_prep(
    const float* __restrict__ w, const float* __restrict__ bias,
    const float* __restrict__ resp, float* __restrict__ ws)
{
    int t = blockIdx.x * 256 + threadIdx.x;     // 0..2047
    const float4* __restrict__ w4 = reinterpret_cast<const float4*>(w);
    float4 v = w4[t];
    int node = t >> 2, pos = t & 3;
    float4 s = make_float4(v.x * kScale, v.y * kScale, v.z * kScale, v.w * kScale);
    *reinterpret_cast<float4*>(ws + node * kStride + pos * 4) = s;
    if (t < kNodes) {
        float b = bias[t], r = resp[t];
        ws[t * kStride + 16] = b * kScale;
        ws[t * kStride + 17] = r;
        ws[t * kStride + 18] = -2.0f * r;
        ws[t * kStride + 19] = 0.0f;
    }
}

// ---------- main ----------
#define DECLP(P) float P##_0,P##_1,P##_2,P##_3,P##_4,P##_5,P##_6,P##_7,      \
    P##_8,P##_9,P##_10,P##_11,P##_12,P##_13,P##_14,P##_15,P##_b,P##_r;

// Uniform-address loads of node IDX's params -> expected to select s_load.
#define LOADP(P, IDX) {                                                      \
    const float* __restrict__ nb = ws + (IDX) * kStride;                     \
    P##_0 =nb[0];  P##_1 =nb[1];  P##_2 =nb[2];  P##_3 =nb[3];               \
    P##_4 =nb[4];  P##_5 =nb[5];  P##_6 =nb[6];  P##_7 =nb[7];               \
    P##_8 =nb[8];  P##_9 =nb[9];  P##_10=nb[10]; P##_11=nb[11];              \
    P##_12=nb[12]; P##_13=nb[13]; P##_14=nb[14]; P##_15=nb[15];              \
    P##_b =nb[16]; P##_r =nb[17]; }

// A0 = oldest window slot (weight j=0, gets overwritten), A15 = previous
// node's value (weight j=15, kept in the FINAL fma -> only op on the chain).
// Chain: fma -> exp2 -> add -> rcp -> fma(-2,u,1) -> mul r  (~45 cyc).
#define NODE_CORE(P, A0,A1,A2,A3,A4,A5,A6,A7,A8,A9,A10,A11,A12,A13,A14,A15) \
    float p0 = fmaf(A0,  P##_0,  P##_b);                                     \
    float p1 = A4  * P##_4;                                                  \
    float p2 = A8  * P##_8;                                                  \
    float p3 = A12 * P##_12;                                                 \
    p0 = fmaf(A1,  P##_1,  p0);  p1 = fmaf(A5,  P##_5,  p1);                 \
    p2 = fmaf(A9,  P##_9,  p2);  p3 = fmaf(A13, P##_13, p3);                 \
    p0 = fmaf(A2,  P##_2,  p0);  p1 = fmaf(A6,  P##_6,  p1);                 \
    p2 = fmaf(A10, P##_10, p2);  p3 = fmaf(A14, P##_14, p3);                 \
    p0 = fmaf(A3,  P##_3,  p0);  p1 = fmaf(A7,  P##_7,  p1);                 \
    p2 = fmaf(A11, P##_11, p2);                                              \
    float pre = (p0 + p1) + (p2 + p3);                                       \
    float acc = fmaf(A15, P##_15, pre);                                      \
    float e = __builtin_amdgcn_exp2f(acc);                                   \
    float u = __builtin_amdgcn_rcpf(e + 1.0f);                               \
    A0 = fmaf(-2.0f, u, 1.0f) * P##_r;

// Phase-1 node: compute node g*16+K with set P, then prefetch node +2 into P.
#define NODE1(P, K, A0,A1,A2,A3,A4,A5,A6,A7,A8,A9,A10,A11,A12,A13,A14,A15) { \
    NODE_CORE(P, A0,A1,A2,A3,A4,A5,A6,A7,A8,A9,A10,A11,A12,A13,A14,A15)      \
    LOADP(P, g * 16 + (K) + 2) }

// Phase-2 node: also capture output into TV; clamp prefetch overrun.
#define NODE2(P, G, K, TV, A0,A1,A2,A3,A4,A5,A6,A7,A8,A9,A10,A11,A12,A13,A14,A15) { \
    NODE_CORE(P, A0,A1,A2,A3,A4,A5,A6,A7,A8,A9,A10,A11,A12,A13,A14,A15)      \
    TV = A0;                                                                 \
    int ni = (G) * 16 + (K) + 2; if (ni >= kNodes) ni = 0;                   \
    LOADP(P, ni) }

#define GROUP1                                                                   \
    NODE1(PA,  0, v0 ,v1 ,v2 ,v3 ,v4 ,v5 ,v6 ,v7 ,v8 ,v9 ,v10,v11,v12,v13,v14,v15) \
    NODE1(PB,  1, v1 ,v2 ,v3 ,v4 ,v5 ,v6 ,v7 ,v8 ,v9 ,v10,v11,v12,v13,v14,v15,v0 ) \
    NODE1(PA,  2, v2 ,v3 ,v4 ,v5 ,v6 ,v7 ,v8 ,v9 ,v10,v11,v12,v13,v14,v15,v0 ,v1 ) \
    NODE1(PB,  3, v3 ,v4 ,v5 ,v6 ,v7 ,v8 ,v9 ,v10,v11,v12,v13,v14,v15,v0 ,v1 ,v2 ) \
    NODE1(PA,  4, v4 ,v5 ,v6 ,v7 ,v8 ,v9 ,v10,v11,v12,v13,v14,v15,v0 ,v1 ,v2 ,v3 ) \
    NODE1(PB,  5, v5 ,v6 ,v7 ,v8 ,v9 ,v10,v11,v12,v13,v14,v15,v0 ,v1 ,v2 ,v3 ,v4 ) \
    NODE1(PA,  6, v6 ,v7 ,v8 ,v9 ,v10,v11,v12,v13,v14,v15,v0 ,v1 ,v2 ,v3 ,v4 ,v5 ) \
    NODE1(PB,  7, v7 ,v8 ,v9 ,v10,v11,v12,v13,v14,v15,v0 ,v1 ,v2 ,v3 ,v4 ,v5 ,v6 ) \
    NODE1(PA,  8, v8 ,v9 ,v10,v11,v12,v13,v14,v15,v0 ,v1 ,v2 ,v3 ,v4 ,v5 ,v6 ,v7 ) \
    NODE1(PB,  9, v9 ,v10,v11,v12,v13,v14,v15,v0 ,v1 ,v2 ,v3 ,v4 ,v5 ,v6 ,v7 ,v8 ) \
    NODE1(PA, 10, v10,v11,v12,v13,v14,v15,v0 ,v1 ,v2 ,v3 ,v4 ,v5 ,v6 ,v7 ,v8 ,v9 ) \
    NODE1(PB, 11, v11,v12,v13,v14,v15,v0 ,v1 ,v2 ,v3 ,v4 ,v5 ,v6 ,v7 ,v8 ,v9 ,v10) \
    NODE1(PA, 12, v12,v13,v14,v15,v0 ,v1 ,v2 ,v3 ,v4 ,v5 ,v6 ,v7 ,v8 ,v9 ,v10,v11) \
    NODE1(PB, 13, v13,v14,v15,v0 ,v1 ,v2 ,v3 ,v4 ,v5 ,v6 ,v7 ,v8 ,v9 ,v10,v11,v12) \
    NODE1(PA, 14, v14,v15,v0 ,v1 ,v2 ,v3 ,v4 ,v5 ,v6 ,v7 ,v8 ,v9 ,v10,v11,v12,v13) \
    NODE1(PB, 15, v15,v0 ,v1 ,v2 ,v3 ,v4 ,v5 ,v6 ,v7 ,v8 ,v9 ,v10,v11,v12,v13,v14)

#define STORE4(G, O) *reinterpret_cast<float4*>(op + ((G) - 28) * 16 + (O)) = \
    make_float4(t0, t1, t2, t3);

#define GROUP2(G)                                                                    \
    NODE2(PA, G,  0, t0, v0 ,v1 ,v2 ,v3 ,v4 ,v5 ,v6 ,v7 ,v8 ,v9 ,v10,v11,v12,v13,v14,v15) \
    NODE2(PB, G,  1, t1, v1 ,v2 ,v3 ,v4 ,v5 ,v6 ,v7 ,v8 ,v9 ,v10,v11,v12,v13,v14,v15,v0 ) \
    NODE2(PA, G,  2, t2, v2 ,v3 ,v4 ,v5 ,v6 ,v7 ,v8 ,v9 ,v10,v11,v12,v13,v14,v15,v0 ,v1 ) \
    NODE2(PB, G,  3, t3, v3 ,v4 ,v5 ,v6 ,v7 ,v8 ,v9 ,v10,v11,v12,v13,v14,v15,v0 ,v1 ,v2 ) \
    STORE4(G, 0)                                                                     \
    NODE2(PA, G,  4, t0, v4 ,v5 ,v6 ,v7 ,v8 ,v9 ,v10,v11,v12,v13,v14,v15,v0 ,v1 ,v2 ,v3 ) \
    NODE2(PB, G,  5, t1, v5 ,v6 ,v7 ,v8 ,v9 ,v10,v11,v12,v13,v14,v15,v0 ,v1 ,v2 ,v3 ,v4 ) \
    NODE2(PA, G,  6, t2, v6 ,v7 ,v8 ,v9 ,v10,v11,v12,v13,v14,v15,v0 ,v1 ,v2 ,v3 ,v4 ,v5 ) \
    NODE2(PB, G,  7, t3, v7 ,v8 ,v9 ,v10,v11,v12,v13,v14,v15,v0 ,v1 ,v2 ,v3 ,v4 ,v5 ,v6 ) \
    STORE4(G, 4)                                                                     \
    NODE2(PA, G,  8, t0, v8 ,v9 ,v10,v11,v12,v13,v14,v15,v0 ,v1 ,v2 ,v3 ,v4 ,v5 ,v6 ,v7 ) \
    NODE2(PB, G,  9, t1, v9 ,v10,v11,v12,v13,v14,v15,v0 ,v1 ,v2 ,v3 ,v4 ,v5 ,v6 ,v7 ,v8 ) \
    NODE2(PA, G, 10, t2, v10,v11,v12,v13,v14,v15,v0 ,v1 ,v2 ,v3 ,v4 ,v5 ,v6 ,v7 ,v8 ,v9 ) \
    NODE2(PB, G, 11, t3, v11,v12,v13,v14,v15,v0 ,v1 ,v2 ,v3 ,v4 ,v5 ,v6 ,v7 ,v8 ,v9 ,v10) \
    STORE4(G, 8)                                                                     \
    NODE2(PA, G, 12, t0, v12,v13,v14,v15,v0 ,v1 ,v2 ,v3 ,v4 ,v5 ,v6 ,v7 ,v8 ,v9 ,v10,v11) \
    NODE2(PB, G, 13, t1, v13,v14,v15,v0 ,v1 ,v2 ,v3 ,v4 ,v5 ,v6 ,v7 ,v8 ,v9 ,v10,v11,v12) \
    NODE2(PA, G, 14, t2, v14,v15,v0 ,v1 ,v2 ,v3 ,v4 ,v5 ,v6 ,v7 ,v8 ,v9 ,v10,v11,v12,v13) \
    NODE2(PB, G, 15, t3, v15,v0 ,v1 ,v2 ,v3 ,v4 ,v5 ,v6 ,v7 ,v8 ,v9 ,v10,v11,v12,v13,v14) \
    STORE4(G, 12)

__global__ __launch_bounds__(64) void neat_fwd(
    const float* __restrict__ x,      // [B, 16]
    const float* __restrict__ ws,     // [512, 20] pre-scaled params
    float* __restrict__ out)          // [B, 64]
{
    const int b = blockIdx.x * 64 + threadIdx.x;

    const float4* __restrict__ x4 = reinterpret_cast<const float4*>(x) + (size_t)b * 4;
    float4 a0 = x4[0], a1 = x4[1], a2 = x4[2], a3 = x4[3];
    float v0  = a0.x, v1  = a0.y, v2  = a0.z, v3  = a0.w;
    float v4  = a1.x, v5  = a1.y, v6  = a1.z, v7  = a1.w;
    float v8  = a2.x, v9  = a2.y, v10 = a2.z, v11 = a2.w;
    float v12 = a3.x, v13 = a3.y, v14 = a3.z, v15 = a3.w;

    float* __restrict__ op = out + (size_t)b * kNOut;

    DECLP(PA) DECLP(PB)
    LOADP(PA, 0)
    LOADP(PB, 1)
    float t0, t1, t2, t3;

    // Phase 1: groups 0..27 — no stores anywhere (keeps uniform loads
    // clobber-free); each group rotates the window back to identity.
    #pragma unroll 1
    for (int g = 0; g < 28; ++g) {
        GROUP1
    }
    // Phase 2: output groups 28..31, compile-time store addresses.
    GROUP2(28)
    GROUP2(29)
    GROUP2(30)
    GROUP2(31)
}

extern "C" void kernel_launch(void* const* d_in, const int* in_sizes, int n_in,
                              void* d_out, int out_size, void* d_ws, size_t ws_size,
                              hipStream_t stream) {
    const float* x    = (const float*)d_in[0];
    const float* w    = (const float*)d_in[1];
    const float* bias = (const float*)d_in[2];
    const float* resp = (const float*)d_in[3];
    float* out = (float*)d_out;
    float* ws  = (float*)d_ws;       // 40960 B used

    hipLaunchKernelGGL(neat_prep, dim3(8), dim3(256), 0, stream, w, bias, resp, ws);
    // 512 blocks x 64 -> 2 independent waves per CU.
    hipLaunchKernelGGL(neat_fwd, dim3(kBatch / 64), dim3(64), 0, stream, x, ws, out);
}

// Round 6
// 98.672 us; speedup vs baseline: 1.8622x; 1.8622x over previous
//
#include <hip/hip_runtime.h>

// NEAT windowed-DAG forward:
//   values[0:16] = x; for i in 0..511: v = tanh(dot(values[i:i+16], w[i]) + b[i]) * r[i]
//   out = values[T-64:T]  (nodes 448..511)
//
// R6: delivery-path scorecard: per-node global=301cyc, LDS(compiler sched)=301,
// LDS(source prefetch, undone by scheduler)=260, SMEM=582 (SMEM is OOO ->
// lgkmcnt(0) on every consume kills double-buffering; scalar K$ thrashes).
// Fix: LDS + HAND-PINNED pipeline. Volatile-asm ds_read_b128 (5/node, depth-3,
// 4 rotating reg sets) + "s_waitcnt lgkmcnt(15)" tied to the consumed set via
// "+v" operands -> scheduler cannot sink loads or hoist consumers. DS returns
// in-order and nothing else in the loop touches lgkmcnt, so the count is exact.

typedef float v4f __attribute__((ext_vector_type(4)));

constexpr int kNodes  = 512;
constexpr int kNOut   = 64;
constexpr int kBatch  = 32768;
constexpr int kStrideF = 20;                    // floats per node slot (80 B)
constexpr int kLdsFloats = (kNodes + 3) * kStrideF + 4;  // prefetch overrun slack
constexpr float kScale = 2.8853900817779268f;   // 2*log2(e)

// Issue the 5 ds_read_b128 for the node at LDS byte address `a` into set S.
// Earlyclobber: dest tuples must not alias the address reg.
#define PREF(S) {                                                             \
    asm volatile(                                                             \
      "ds_read_b128 %0, %5 offset:0\n\t"                                      \
      "ds_read_b128 %1, %5 offset:16\n\t"                                     \
      "ds_read_b128 %2, %5 offset:32\n\t"                                     \
      "ds_read_b128 %3, %5 offset:48\n\t"                                     \
      "ds_read_b128 %4, %5 offset:64"                                         \
      : "=&v"(q0[S]), "=&v"(q1[S]), "=&v"(q2[S]), "=&v"(q3[S]), "=&v"(q4[S])  \
      : "v"(a));                                                              \
    a += kStrideF * 4; }

// Wait until set S's reads returned: after PREF of node i+3, the 15 newer
// reads (nodes i+1,i+2,i+3) may remain outstanding. In-order DS returns make
// lgkmcnt(15) == "set i has landed". "+v" ties consumers to this asm.
#define WAITQ(S)                                                              \
    asm volatile("s_waitcnt lgkmcnt(15)"                                      \
      : "+v"(q0[S]), "+v"(q1[S]), "+v"(q2[S]), "+v"(q3[S]), "+v"(q4[S]));

// Node i = g*16+K. A0 = oldest slot (weight j=0, overwritten with result),
// A15 = previous node (weight j=15, in the FINAL fma -> only op on the serial
// chain). q4 = (b*scale, r, -2r, pad). Chain: fma->exp2->add->rcp->fma.
#define NODE(K, A0,A1,A2,A3,A4,A5,A6,A7,A8,A9,A10,A11,A12,A13,A14,A15) {     \
    PREF(((K)+3)&3)                                                          \
    WAITQ((K)&3)                                                             \
    const int s = (K)&3;                                                     \
    v4f qa = q0[s], qb = q1[s], qc = q2[s], qd = q3[s], qm = q4[s];          \
    float p0 = fmaf(A0,  qa.x, qm.x);                                        \
    float p1 = A4  * qb.x;                                                   \
    float p2 = A8  * qc.x;                                                   \
    float p3 = A12 * qd.x;                                                   \
    p0 = fmaf(A1,  qa.y, p0);  p1 = fmaf(A5,  qb.y, p1);                     \
    p2 = fmaf(A9,  qc.y, p2);  p3 = fmaf(A13, qd.y, p3);                     \
    p0 = fmaf(A2,  qa.z, p0);  p1 = fmaf(A6,  qb.z, p1);                     \
    p2 = fmaf(A10, qc.z, p2);  p3 = fmaf(A14, qd.z, p3);                     \
    p0 = fmaf(A3,  qa.w, p0);  p1 = fmaf(A7,  qb.w, p1);                     \
    p2 = fmaf(A11, qc.w, p2);                                                \
    float pre = (p0 + p1) + (p2 + p3);                                       \
    float acc = fmaf(A15, qd.w, pre);       /* serial chain starts here */   \
    float e = __builtin_amdgcn_exp2f(acc);                                   \
    float u = __builtin_amdgcn_rcpf(e + 1.0f);                               \
    A0 = fmaf(qm.z, u, qm.y); }

__global__ __launch_bounds__(128) void neat_fwd(
    const float* __restrict__ x,      // [B, 16]
    const float* __restrict__ w,      // [512, 16]
    const float* __restrict__ bias,   // [512]
    const float* __restrict__ resp,   // [512]
    float* __restrict__ out)          // [B, 64]
{
    __shared__ float lds[kLdsFloats];

    const int t = threadIdx.x;

    // ---- Stage params into LDS, pre-scaled by 2*log2(e) ----
    const float4* __restrict__ w4 = reinterpret_cast<const float4*>(w);
    #pragma unroll
    for (int j = 0; j < 16; ++j) {
        int i4 = t + j * 128;                 // [0, 2048)
        float4 v = w4[i4];
        int node = i4 >> 2, pos = (i4 & 3) << 2;
        float4 s = make_float4(v.x * kScale, v.y * kScale, v.z * kScale, v.w * kScale);
        *reinterpret_cast<float4*>(lds + node * kStrideF + pos) = s;
    }
    #pragma unroll
    for (int j = 0; j < 4; ++j) {
        int n = t + j * 128;
        float b = bias[n], r = resp[n];
        lds[n * kStrideF + 16] = b * kScale;
        lds[n * kStrideF + 17] = r;
        lds[n * kStrideF + 18] = -2.0f * r;
        lds[n * kStrideF + 19] = 0.0f;
    }

    const int b = blockIdx.x * blockDim.x + t;
    const float4* __restrict__ x4 = reinterpret_cast<const float4*>(x) + (size_t)b * 4;
    float4 a0 = x4[0], a1 = x4[1], a2 = x4[2], a3 = x4[3];
    float v0  = a0.x, v1  = a0.y, v2  = a0.z, v3  = a0.w;
    float v4  = a1.x, v5  = a1.y, v6  = a1.z, v7  = a1.w;
    float v8  = a2.x, v9  = a2.y, v10 = a2.z, v11 = a2.w;
    float v12 = a3.x, v13 = a3.y, v14 = a3.z, v15 = a3.w;

    float* __restrict__ op = out + (size_t)b * kNOut;

    __syncthreads();   // also drains staging ds_writes (compiler lgkmcnt(0))

    // LDS byte address cursor for the next node to prefetch. AMDGCN lowers
    // addrspace(3)->flat as {aperture_hi32, lds_offset}, so the low 32 bits
    // of the cast are the DS byte address.
    unsigned int a = (unsigned int)(unsigned long long)(&lds[0]);

    v4f q0[4], q1[4], q2[4], q3[4], q4[4];
    PREF(0) PREF(1) PREF(2)    // nodes 0,1,2 in flight

    #pragma unroll 1
    for (int g = 0; g < 32; ++g) {
        NODE( 0, v0 ,v1 ,v2 ,v3 ,v4 ,v5 ,v6 ,v7 ,v8 ,v9 ,v10,v11,v12,v13,v14,v15)
        NODE( 1, v1 ,v2 ,v3 ,v4 ,v5 ,v6 ,v7 ,v8 ,v9 ,v10,v11,v12,v13,v14,v15,v0 )
        NODE( 2, v2 ,v3 ,v4 ,v5 ,v6 ,v7 ,v8 ,v9 ,v10,v11,v12,v13,v14,v15,v0 ,v1 )
        NODE( 3, v3 ,v4 ,v5 ,v6 ,v7 ,v8 ,v9 ,v10,v11,v12,v13,v14,v15,v0 ,v1 ,v2 )
        NODE( 4, v4 ,v5 ,v6 ,v7 ,v8 ,v9 ,v10,v11,v12,v13,v14,v15,v0 ,v1 ,v2 ,v3 )
        NODE( 5, v5 ,v6 ,v7 ,v8 ,v9 ,v10,v11,v12,v13,v14,v15,v0 ,v1 ,v2 ,v3 ,v4 )
        NODE( 6, v6 ,v7 ,v8 ,v9 ,v10,v11,v12,v13,v14,v15,v0 ,v1 ,v2 ,v3 ,v4 ,v5 )
        NODE( 7, v7 ,v8 ,v9 ,v10,v11,v12,v13,v14,v15,v0 ,v1 ,v2 ,v3 ,v4 ,v5 ,v6 )
        NODE( 8, v8 ,v9 ,v10,v11,v12,v13,v14,v15,v0 ,v1 ,v2 ,v3 ,v4 ,v5 ,v6 ,v7 )
        NODE( 9, v9 ,v10,v11,v12,v13,v14,v15,v0 ,v1 ,v2 ,v3 ,v4 ,v5 ,v6 ,v7 ,v8 )
        NODE(10, v10,v11,v12,v13,v14,v15,v0 ,v1 ,v2 ,v3 ,v4 ,v5 ,v6 ,v7 ,v8 ,v9 )
        NODE(11, v11,v12,v13,v14,v15,v0 ,v1 ,v2 ,v3 ,v4 ,v5 ,v6 ,v7 ,v8 ,v9 ,v10)
        NODE(12, v12,v13,v14,v15,v0 ,v1 ,v2 ,v3 ,v4 ,v5 ,v6 ,v7 ,v8 ,v9 ,v10,v11)
        NODE(13, v13,v14,v15,v0 ,v1 ,v2 ,v3 ,v4 ,v5 ,v6 ,v7 ,v8 ,v9 ,v10,v11,v12)
        NODE(14, v14,v15,v0 ,v1 ,v2 ,v3 ,v4 ,v5 ,v6 ,v7 ,v8 ,v9 ,v10,v11,v12,v13)
        NODE(15, v15,v0 ,v1 ,v2 ,v3 ,v4 ,v5 ,v6 ,v7 ,v8 ,v9 ,v10,v11,v12,v13,v14)
        // After the group, window slot k == value of node g*16+k.
        if (g >= 28) {
            float4* o4 = reinterpret_cast<float4*>(op + (g - 28) * 16);
            o4[0] = make_float4(v0,  v1,  v2,  v3);
            o4[1] = make_float4(v4,  v5,  v6,  v7);
            o4[2] = make_float4(v8,  v9,  v10, v11);
            o4[3] = make_float4(v12, v13, v14, v15);
        }
    }

    // Drain overrun prefetches (nodes 512..514) so no ds_read lands in
    // VGPRs after the wave is deallocated.
    asm volatile("s_waitcnt lgkmcnt(0)" ::: "memory");
}

extern "C" void kernel_launch(void* const* d_in, const int* in_sizes, int n_in,
                              void* d_out, int out_size, void* d_ws, size_t ws_size,
                              hipStream_t stream) {
    const float* x    = (const float*)d_in[0];
    const float* w    = (const float*)d_in[1];
    const float* bias = (const float*)d_in[2];
    const float* resp = (const float*)d_in[3];
    float* out = (float*)d_out;
    // in_sizes[4] (src_idx) encodes the fixed windowed topology; hardcoded above.
    dim3 block(128);
    dim3 grid(kBatch / 128);   // 256 blocks -> 1 per CU, 2 waves/CU
    hipLaunchKernelGGL(neat_fwd, grid, block, 0, stream, x, w, bias, resp, out);
}